// Round 1
// 347.345 us; speedup vs baseline: 1.0460x; 1.0460x over previous
//
#include <hip/hip_runtime.h>
#include <hip/hip_bf16.h>

#define B 2
#define N 20000
#define M 4096
#define S 2
#define K 25
#define J 64
#define KJ (K*J)        // 1600
#define TC 32           // MLP column tile

#define CHUNK 10176     // xf rows staged in LDS = 162816 B (<= 163840)
#define GPB   64        // groups per block
#define NTH   1024      // 16 single-wave teams

// ---------------- Kernel A: prep ----------------
__global__ __launch_bounds__(256) void prep_kernel(
    const float* __restrict__ xyz, const float* __restrict__ feature,
    const float* __restrict__ new_xyz, const float* __restrict__ conv_w,
    const float* __restrict__ w0, const float* __restrict__ w1,
    __hip_bfloat16* __restrict__ xfh, float* __restrict__ conv_wT,
    float* __restrict__ w0T, float* __restrict__ w1T,
    float* __restrict__ out_newxyz) {
    const int T1 = B * N * 8;     // 320000
    const int T2 = 208 * 64;      // 13312
    const int T3 = B * M * 3;     // 24576
    const int T4 = 128 * 128;     // 16384
    const int T5 = 128 * 256;     // 32768
    int e = blockIdx.x * blockDim.x + threadIdx.x;
    if (e < T1) {
        int r = e >> 3, t = e & 7;
        float v = (t < 2) ? xyz[r * 3 + t] : feature[r * 6 + (t - 2)];
        xfh[e] = __float2bfloat16(v);
    } else if (e < T1 + T2) {
        int e2 = e - T1;
        int i = e2 >> 6, o = e2 & 63;           // i = k*8+c
        conv_wT[e2] = (i < 200) ? conv_w[o * 200 + (i & 7) * 25 + (i >> 3)] : 0.f;
    } else if (e < T1 + T2 + T3) {
        int e3 = e - T1 - T2;
        out_newxyz[e3] = new_xyz[e3];
    } else if (e < T1 + T2 + T3 + T4) {
        int e4 = e - T1 - T2 - T3;
        int c = e4 >> 7, o = e4 & 127;          // w0T[c][o]
        w0T[e4] = w0[o * 128 + c];
    } else if (e < T1 + T2 + T3 + T4 + T5) {
        int e5 = e - T1 - T2 - T3 - T4;
        int c = e5 >> 8, o = e5 & 255;          // w1T[c][o]
        w1T[e5] = w1[o * 128 + c];
    }
}

// ---------------- Kernel B: hybrid LDS/L2 gather + conv + relu ----------------
// 256 blocks x 64 groups. Rows [0,CHUNK) of this block's b-table live in LDS
// (50.9% hit); only misses issue global 16B requests -> L2 request floor
// 26.2M*0.491/153.6G = 84 us (vs 171 us all-global). 16 free-running
// single-wave teams per block: no post-stage barriers, conv consumes the
// per-k accumulators via readlane broadcasts (no snf/spart LDS needed).
__global__ __launch_bounds__(NTH) void gather_conv_kernel(
    const int* __restrict__ idx, const float* __restrict__ weight,
    const float* __restrict__ new_xyz, const uint4* __restrict__ xfh,
    const float* __restrict__ conv_wT, const float* __restrict__ conv_b,
    float* __restrict__ xmid) {
    __shared__ uint4 chunk[CHUNK];   // 162816 B

    const int tid = threadIdx.x;
    const int g0  = blockIdx.x * GPB;          // 64 consecutive g: same (s,b)
    const int b   = (g0 >> 12) & (B - 1);
    const uint4* xfb = xfh + (size_t)b * N;

    for (int r = tid; r < CHUNK; r += NTH) chunk[r] = xfb[r];
    __syncthreads();

    const int team = tid >> 6;                 // 16 teams, one wave each
    const int lane = tid & 63;
    const float bo = conv_b[lane];             // o = lane

    for (int u = 0; u < GPB / (NTH / 64); ++u) {      // 4 groups per team
        const int g = g0 + team * (GPB / (NTH / 64)) + u;
        const int m = g & (M - 1);
        const int s = g >> 13;
        const float cx = new_xyz[(b * M + m) * 3 + 0];
        const float cy = new_xyz[(b * M + m) * 3 + 1];
        float acc2 = bo;

        // passes p=0..2: k = p*8 + (lane>>3); pass p=3: k=24 on lanes 0..7
        #pragma unroll 1
        for (int p = 0; p < 4; ++p) {
            const int myk = p * 8 + (lane >> 3);
            const bool act = (p < 3) || (lane < 8);
            float acc[8] = {0.f,0.f,0.f,0.f,0.f,0.f,0.f,0.f};
            if (act) {
                const size_t base = (size_t)g * KJ + (size_t)myk * J + (lane & 7) * 8;
                const int4   ia = *(const int4*)  (idx + base);
                const int4   ib = *(const int4*)  (idx + base + 4);
                const float4 wa = *(const float4*)(weight + base);
                const float4 wb = *(const float4*)(weight + base + 4);
                const int   ids[8] = {ia.x, ia.y, ia.z, ia.w, ib.x, ib.y, ib.z, ib.w};
                const float wsv[8] = {wa.x, wa.y, wa.z, wa.w, wb.x, wb.y, wb.z, wb.w};

                uint4 rr[8];
                #pragma unroll
                for (int j = 0; j < 8; ++j)
                    if (ids[j] < CHUNK) rr[j] = chunk[ids[j]];       // LDS hit
                #pragma unroll
                for (int j = 0; j < 8; ++j)
                    if (ids[j] >= CHUNK) rr[j] = xfb[ids[j]];        // exec-masked miss

                #pragma unroll
                for (int j = 0; j < 8; ++j) {
                    const uint4 r = rr[j];
                    const float w = wsv[j];
                    acc[0] = fmaf(w, __uint_as_float(r.x << 16),         acc[0]);
                    acc[1] = fmaf(w, __uint_as_float(r.x & 0xffff0000u), acc[1]);
                    acc[2] = fmaf(w, __uint_as_float(r.y << 16),         acc[2]);
                    acc[3] = fmaf(w, __uint_as_float(r.y & 0xffff0000u), acc[3]);
                    acc[4] = fmaf(w, __uint_as_float(r.z << 16),         acc[4]);
                    acc[5] = fmaf(w, __uint_as_float(r.z & 0xffff0000u), acc[5]);
                    acc[6] = fmaf(w, __uint_as_float(r.w << 16),         acc[6]);
                    acc[7] = fmaf(w, __uint_as_float(r.w & 0xffff0000u), acc[7]);
                }
                #pragma unroll
                for (int d = 1; d < 8; d <<= 1) {
                    #pragma unroll
                    for (int c = 0; c < 8; ++c) acc[c] += __shfl_xor(acc[c], d, 64);
                }
                if ((lane & 7) == 0) { acc[0] -= cx; acc[1] -= cy; }
            }
            // conv partial for this pass's k's; readlane broadcast from
            // holder lane kk*8 (compile-time lane via unrolled kk).
            const int nk = (p < 3) ? 8 : 1;
            #pragma unroll
            for (int kk = 0; kk < 8; ++kk) {
                if (kk < nk) {
                    const float* wrow = conv_wT + (size_t)((p * 8 + kk) * 8) * 64 + lane;
                    #pragma unroll
                    for (int c = 0; c < 8; ++c) {
                        const float v = __shfl(acc[c], kk * 8, 64);
                        acc2 = fmaf(v, wrow[c * 64], acc2);
                    }
                }
            }
        }
        xmid[((size_t)(b * M + m)) * 128 + s * 64 + lane] = fmaxf(acc2, 0.f);
    }
}

// ---------------- Kernel C0: MLP0 + relu (in-place xmid [col][128]) ----------------
__global__ __launch_bounds__(256) void mlp0_kernel(
    float* __restrict__ xmid,
    const float* __restrict__ w0T, const float* __restrict__ b0) {
    __shared__ float ws[128 * 128];   // 64 KB, [c][o]
    __shared__ float xs[128 * 32];    // 16 KB, [c][col]

    int tid = threadIdx.x;
    int col0 = blockIdx.x * TC;

    {
        const float4* w4 = (const float4*)w0T;
        float4* ws4 = (float4*)ws;
        #pragma unroll
        for (int i = 0; i < 16; ++i) ws4[tid + 256 * i] = w4[tid + 256 * i];
    }
    {
        const float4* xm4 = (const float4*)(xmid + (size_t)col0 * 128);
        #pragma unroll
        for (int r = tid; r < 1024; r += 256) {
            int lc = r >> 5, c4 = r & 31;
            float4 v = xm4[lc * 32 + c4];
            int c = c4 * 4;
            xs[(c + 0) * 32 + lc] = v.x;
            xs[(c + 1) * 32 + lc] = v.y;
            xs[(c + 2) * 32 + lc] = v.z;
            xs[(c + 3) * 32 + lc] = v.w;
        }
    }
    __syncthreads();

    int og = tid >> 3, cg = tid & 7;
    int o0 = og * 4, lc0 = cg * 4;
    float acc[4][4];
    #pragma unroll
    for (int i = 0; i < 4; ++i) {
        float bv = b0[o0 + i];
        #pragma unroll
        for (int u = 0; u < 4; ++u) acc[i][u] = bv;
    }
    for (int c = 0; c < 128; ++c) {
        float4 xv = *(const float4*)&xs[c * 32 + lc0];
        float4 wv = *(const float4*)&ws[c * 128 + o0];
        acc[0][0] = fmaf(wv.x, xv.x, acc[0][0]);
        acc[0][1] = fmaf(wv.x, xv.y, acc[0][1]);
        acc[0][2] = fmaf(wv.x, xv.z, acc[0][2]);
        acc[0][3] = fmaf(wv.x, xv.w, acc[0][3]);
        acc[1][0] = fmaf(wv.y, xv.x, acc[1][0]);
        acc[1][1] = fmaf(wv.y, xv.y, acc[1][1]);
        acc[1][2] = fmaf(wv.y, xv.z, acc[1][2]);
        acc[1][3] = fmaf(wv.y, xv.w, acc[1][3]);
        acc[2][0] = fmaf(wv.z, xv.x, acc[2][0]);
        acc[2][1] = fmaf(wv.z, xv.y, acc[2][1]);
        acc[2][2] = fmaf(wv.z, xv.z, acc[2][2]);
        acc[2][3] = fmaf(wv.z, xv.w, acc[2][3]);
        acc[3][0] = fmaf(wv.w, xv.x, acc[3][0]);
        acc[3][1] = fmaf(wv.w, xv.y, acc[3][1]);
        acc[3][2] = fmaf(wv.w, xv.z, acc[3][2]);
        acc[3][3] = fmaf(wv.w, xv.w, acc[3][3]);
    }
    #pragma unroll
    for (int u = 0; u < 4; ++u) {
        float4 v = make_float4(fmaxf(acc[0][u], 0.f), fmaxf(acc[1][u], 0.f),
                               fmaxf(acc[2][u], 0.f), fmaxf(acc[3][u], 0.f));
        *(float4*)&xmid[(size_t)(col0 + lc0 + u) * 128 + o0] = v;
    }
}

// ---------------- Kernel C1: MLP1 + relu + store (o-split) ----------------
__global__ __launch_bounds__(256) void mlp1_kernel(
    const float* __restrict__ xmid,
    const float* __restrict__ w1T, const float* __restrict__ b1,
    float* __restrict__ out_rf) {
    __shared__ float ws[128 * 128];   // 64 KB, [c][o-half]
    __shared__ float xs[128 * 32];    // 16 KB

    int tid = threadIdx.x;
    int bx = blockIdx.x;
    int col0 = (bx >> 1) * TC;
    int oH = (bx & 1) * 128;

    {
        for (int i = tid; i < 4096; i += 256) {
            int c = i >> 5, q = i & 31;
            *(float4*)&ws[c * 128 + q * 4] = *(const float4*)&w1T[c * 256 + oH + q * 4];
        }
    }
    {
        const float4* xm4 = (const float4*)(xmid + (size_t)col0 * 128);
        #pragma unroll
        for (int r = tid; r < 1024; r += 256) {
            int lc = r >> 5, c4 = r & 31;
            float4 v = xm4[lc * 32 + c4];
            int c = c4 * 4;
            xs[(c + 0) * 32 + lc] = v.x;
            xs[(c + 1) * 32 + lc] = v.y;
            xs[(c + 2) * 32 + lc] = v.z;
            xs[(c + 3) * 32 + lc] = v.w;
        }
    }
    __syncthreads();

    int og = tid >> 3, cg = tid & 7;
    int o0 = og * 4, lc0 = cg * 4;
    float acc[4][4];
    #pragma unroll
    for (int i = 0; i < 4; ++i) {
        float bv = b1[oH + o0 + i];
        #pragma unroll
        for (int u = 0; u < 4; ++u) acc[i][u] = bv;
    }
    for (int c = 0; c < 128; ++c) {
        float4 xv = *(const float4*)&xs[c * 32 + lc0];
        float4 wv = *(const float4*)&ws[c * 128 + o0];
        acc[0][0] = fmaf(wv.x, xv.x, acc[0][0]);
        acc[0][1] = fmaf(wv.x, xv.y, acc[0][1]);
        acc[0][2] = fmaf(wv.x, xv.z, acc[0][2]);
        acc[0][3] = fmaf(wv.x, xv.w, acc[0][3]);
        acc[1][0] = fmaf(wv.y, xv.x, acc[1][0]);
        acc[1][1] = fmaf(wv.y, xv.y, acc[1][1]);
        acc[1][2] = fmaf(wv.y, xv.z, acc[1][2]);
        acc[1][3] = fmaf(wv.y, xv.w, acc[1][3]);
        acc[2][0] = fmaf(wv.z, xv.x, acc[2][0]);
        acc[2][1] = fmaf(wv.z, xv.y, acc[2][1]);
        acc[2][2] = fmaf(wv.z, xv.z, acc[2][2]);
        acc[2][3] = fmaf(wv.z, xv.w, acc[2][3]);
        acc[3][0] = fmaf(wv.w, xv.x, acc[3][0]);
        acc[3][1] = fmaf(wv.w, xv.y, acc[3][1]);
        acc[3][2] = fmaf(wv.w, xv.z, acc[3][2]);
        acc[3][3] = fmaf(wv.w, xv.w, acc[3][3]);
    }
    #pragma unroll
    for (int u = 0; u < 4; ++u) {
        float4 v = make_float4(fmaxf(acc[0][u], 0.f), fmaxf(acc[1][u], 0.f),
                               fmaxf(acc[2][u], 0.f), fmaxf(acc[3][u], 0.f));
        *(float4*)&out_rf[(size_t)(col0 + lc0 + u) * 256 + oH + o0] = v;
    }
}

extern "C" void kernel_launch(void* const* d_in, const int* in_sizes, int n_in,
                              void* d_out, int out_size, void* d_ws, size_t ws_size,
                              hipStream_t stream) {
    const float* xyz     = (const float*)d_in[0];
    const float* feature = (const float*)d_in[1];
    const float* new_xyz = (const float*)d_in[2];
    const int*   idx     = (const int*)  d_in[3];
    const float* weight  = (const float*)d_in[4];
    const float* conv_w  = (const float*)d_in[5];
    const float* conv_b  = (const float*)d_in[6];
    const float* mlp_w0  = (const float*)d_in[7];
    const float* mlp_b0  = (const float*)d_in[8];
    const float* mlp_w1  = (const float*)d_in[9];
    const float* mlp_b1  = (const float*)d_in[10];

    float* out    = (float*)d_out;
    float* out_rf = out + (size_t)B * M * 3;

    float* wsf = (float*)d_ws;
    __hip_bfloat16* xfh = (__hip_bfloat16*)wsf;  // 320000 bf16
    float* conv_wT = wsf + 160000;               // 13312
    float* xmid    = conv_wT + 13312;            // B*M*128, [col][c]
    float* w0T     = xmid + 1048576;             // 16384
    float* w1T     = w0T + 16384;                // 32768

    {
        int total = 320000 + 13312 + 24576 + 16384 + 32768;
        int blocks = (total + 255) / 256;
        prep_kernel<<<blocks, 256, 0, stream>>>(xyz, feature, new_xyz, conv_w,
                                                mlp_w0, mlp_w1,
                                                xfh, conv_wT, w0T, w1T, out);
    }
    {
        int blocks = (S * B * M) / GPB;         // 256
        gather_conv_kernel<<<blocks, NTH, 0, stream>>>(idx, weight, new_xyz,
                                                       (const uint4*)xfh,
                                                       conv_wT, conv_b, xmid);
    }
    {
        mlp0_kernel<<<(B * M) / TC, 256, 0, stream>>>(xmid, w0T, mlp_b0);
    }
    {
        mlp1_kernel<<<2 * (B * M) / TC, 256, 0, stream>>>(xmid, w1T, mlp_b1, out_rf);
    }
}

// Round 3
// 345.428 us; speedup vs baseline: 1.0518x; 1.0056x over previous
//
#include <hip/hip_runtime.h>
#include <hip/hip_bf16.h>

#define B 2
#define N 20000
#define M 4096
#define S 2
#define K 25
#define J 64
#define KJ (K*J)        // 1600
#define TC 32           // MLP column tile

#define CHUNK 10176     // xf rows staged in LDS = 162816 B (<= 163840)
#define GPB   64        // groups per block
#define NTH   1024      // 16 single-wave teams

typedef int   iv4 __attribute__((ext_vector_type(4)));
typedef float fv4 __attribute__((ext_vector_type(4)));

// ---------------- Kernel A: prep ----------------
__global__ __launch_bounds__(256) void prep_kernel(
    const float* __restrict__ xyz, const float* __restrict__ feature,
    const float* __restrict__ new_xyz, const float* __restrict__ conv_w,
    const float* __restrict__ w0, const float* __restrict__ w1,
    __hip_bfloat16* __restrict__ xfh, float* __restrict__ conv_wT,
    float* __restrict__ w0T, float* __restrict__ w1T,
    float* __restrict__ out_newxyz) {
    const int T1 = B * N * 8;     // 320000
    const int T2 = 208 * 64;      // 13312 (52 float4-rows x 64 o)
    const int T3 = B * M * 3;     // 24576
    const int T4 = 128 * 128;     // 16384
    const int T5 = 128 * 256;     // 32768
    int e = blockIdx.x * blockDim.x + threadIdx.x;
    if (e < T1) {
        int r = e >> 3, t = e & 7;
        float v = (t < 2) ? xyz[r * 3 + t] : feature[r * 6 + (t - 2)];
        xfh[e] = __float2bfloat16(v);
    } else if (e < T1 + T2) {
        // float4-packed conv weights: cw4[i4][o][t], i = i4*4+t, i = k*8+c
        int e2 = e - T1;
        int i4 = e2 >> 8;          // [0,52)
        int rem = e2 & 255;
        int o = rem >> 2, t = rem & 3;
        int i = i4 * 4 + t;
        conv_wT[e2] = (i < 200) ? conv_w[o * 200 + (i & 7) * 25 + (i >> 3)] : 0.f;
    } else if (e < T1 + T2 + T3) {
        int e3 = e - T1 - T2;
        out_newxyz[e3] = new_xyz[e3];
    } else if (e < T1 + T2 + T3 + T4) {
        int e4 = e - T1 - T2 - T3;
        int c = e4 >> 7, o = e4 & 127;          // w0T[c][o]
        w0T[e4] = w0[o * 128 + c];
    } else if (e < T1 + T2 + T3 + T4 + T5) {
        int e5 = e - T1 - T2 - T3 - T4;
        int c = e5 >> 8, o = e5 & 255;          // w1T[c][o]
        w1T[e5] = w1[o * 128 + c];
    }
}

// ---------------- Kernel B: hybrid LDS/L2 gather + conv + relu ----------------
// 256 blocks x 64 groups. Rows [0,CHUNK) of this block's b-table in LDS (50.9%
// hit). Global misses: batched sc0 asm (no L1 allocate -> conv weights stay
// L1-resident); hit lanes clamped to uniform row CHUNK (coalesces to 1 req).
// idx/weight streams nontemporal (no L1 allocate). Conv weights float4-packed
// (52 loads/group, L1-hot). L2 request budget ~= 12.9M misses + ~2M streams.
__global__ __launch_bounds__(NTH) void gather_conv_kernel(
    const int* __restrict__ idx, const float* __restrict__ weight,
    const float* __restrict__ new_xyz, const uint4* __restrict__ xfh,
    const float* __restrict__ conv_wT, const float* __restrict__ conv_b,
    float* __restrict__ xmid) {
    __shared__ uint4 chunk[CHUNK];   // 162816 B

    const int tid = threadIdx.x;
    const int g0  = blockIdx.x * GPB;          // 64 consecutive g: same (s,b)
    const int b   = (g0 >> 12) & (B - 1);
    const uint4* xfb = xfh + (size_t)b * N;

    for (int r = tid; r < CHUNK; r += NTH) chunk[r] = xfb[r];
    __syncthreads();

    const int team = tid >> 6;                 // 16 teams, one wave each
    const int lane = tid & 63;
    const float bo = conv_b[lane];             // o = lane
    const float4* cw4 = (const float4*)conv_wT;

    for (int u = 0; u < GPB / (NTH / 64); ++u) {      // 4 groups per team
        const int g = g0 + team * (GPB / (NTH / 64)) + u;
        const int m = g & (M - 1);
        const int s = g >> 13;
        const float cx = new_xyz[(b * M + m) * 3 + 0];
        const float cy = new_xyz[(b * M + m) * 3 + 1];
        float acc2 = bo;

        // passes p=0..2: k = p*8 + (lane>>3); pass p=3: k=24 on lanes 0..7
        #pragma unroll 1
        for (int p = 0; p < 4; ++p) {
            const int myk = p * 8 + (lane >> 3);
            const bool act = (p < 3) || (lane < 8);
            int   ids[8];
            float wsv[8];
            if (act) {
                const size_t base = (size_t)g * KJ + (size_t)myk * J + (lane & 7) * 8;
                const iv4 ia = __builtin_nontemporal_load((const iv4*)(idx + base));
                const iv4 ib = __builtin_nontemporal_load((const iv4*)(idx + base) + 1);
                const fv4 wa = __builtin_nontemporal_load((const fv4*)(weight + base));
                const fv4 wb = __builtin_nontemporal_load((const fv4*)(weight + base) + 1);
                ids[0] = ia.x; ids[1] = ia.y; ids[2] = ia.z; ids[3] = ia.w;
                ids[4] = ib.x; ids[5] = ib.y; ids[6] = ib.z; ids[7] = ib.w;
                wsv[0] = wa.x; wsv[1] = wa.y; wsv[2] = wa.z; wsv[3] = wa.w;
                wsv[4] = wb.x; wsv[5] = wb.y; wsv[6] = wb.z; wsv[7] = wb.w;
            } else {
                #pragma unroll
                for (int j = 0; j < 8; ++j) { ids[j] = CHUNK; wsv[j] = 0.f; }
            }

            // LDS hits (exec-masked)
            uint4 rr[8];
            #pragma unroll
            for (int j = 0; j < 8; ++j)
                if (ids[j] < CHUNK) rr[j] = chunk[ids[j]];

            // global path, all lanes: hit lanes clamp to uniform row CHUNK
            // (TA-coalesced to one request); sc0 = no L1 allocate.
            {
                const int ic0 = (ids[0] > CHUNK) ? ids[0] : CHUNK;
                const int ic1 = (ids[1] > CHUNK) ? ids[1] : CHUNK;
                const int ic2 = (ids[2] > CHUNK) ? ids[2] : CHUNK;
                const int ic3 = (ids[3] > CHUNK) ? ids[3] : CHUNK;
                const int ic4 = (ids[4] > CHUNK) ? ids[4] : CHUNK;
                const int ic5 = (ids[5] > CHUNK) ? ids[5] : CHUNK;
                const int ic6 = (ids[6] > CHUNK) ? ids[6] : CHUNK;
                const int ic7 = (ids[7] > CHUNK) ? ids[7] : CHUNK;
                const uint4* a0 = xfb + ic0;
                const uint4* a1 = xfb + ic1;
                const uint4* a2 = xfb + ic2;
                const uint4* a3 = xfb + ic3;
                const uint4* a4 = xfb + ic4;
                const uint4* a5 = xfb + ic5;
                const uint4* a6 = xfb + ic6;
                const uint4* a7 = xfb + ic7;
                uint4 r0, r1, r2, r3, r4, r5, r6, r7;
                asm volatile(
                    "global_load_dwordx4 %0, %8, off sc0\n\t"
                    "global_load_dwordx4 %1, %9, off sc0\n\t"
                    "global_load_dwordx4 %2, %10, off sc0\n\t"
                    "global_load_dwordx4 %3, %11, off sc0\n\t"
                    "global_load_dwordx4 %4, %12, off sc0\n\t"
                    "global_load_dwordx4 %5, %13, off sc0\n\t"
                    "global_load_dwordx4 %6, %14, off sc0\n\t"
                    "global_load_dwordx4 %7, %15, off sc0\n\t"
                    "s_waitcnt vmcnt(0)"
                    : "=&v"(r0), "=&v"(r1), "=&v"(r2), "=&v"(r3),
                      "=&v"(r4), "=&v"(r5), "=&v"(r6), "=&v"(r7)
                    : "v"(a0), "v"(a1), "v"(a2), "v"(a3),
                      "v"(a4), "v"(a5), "v"(a6), "v"(a7));
                if (ids[0] >= CHUNK) rr[0] = r0;
                if (ids[1] >= CHUNK) rr[1] = r1;
                if (ids[2] >= CHUNK) rr[2] = r2;
                if (ids[3] >= CHUNK) rr[3] = r3;
                if (ids[4] >= CHUNK) rr[4] = r4;
                if (ids[5] >= CHUNK) rr[5] = r5;
                if (ids[6] >= CHUNK) rr[6] = r6;
                if (ids[7] >= CHUNK) rr[7] = r7;
            }

            float acc[8] = {0.f,0.f,0.f,0.f,0.f,0.f,0.f,0.f};
            #pragma unroll
            for (int j = 0; j < 8; ++j) {
                const uint4 r = rr[j];
                const float w = wsv[j];
                acc[0] = fmaf(w, __uint_as_float(r.x << 16),         acc[0]);
                acc[1] = fmaf(w, __uint_as_float(r.x & 0xffff0000u), acc[1]);
                acc[2] = fmaf(w, __uint_as_float(r.y << 16),         acc[2]);
                acc[3] = fmaf(w, __uint_as_float(r.y & 0xffff0000u), acc[3]);
                acc[4] = fmaf(w, __uint_as_float(r.z << 16),         acc[4]);
                acc[5] = fmaf(w, __uint_as_float(r.z & 0xffff0000u), acc[5]);
                acc[6] = fmaf(w, __uint_as_float(r.w << 16),         acc[6]);
                acc[7] = fmaf(w, __uint_as_float(r.w & 0xffff0000u), acc[7]);
            }
            #pragma unroll
            for (int d = 1; d < 8; d <<= 1) {
                #pragma unroll
                for (int c = 0; c < 8; ++c) acc[c] += __shfl_xor(acc[c], d, 64);
            }
            if ((lane & 7) == 0) { acc[0] -= cx; acc[1] -= cy; }

            // conv partial: float4-packed weights, readlane broadcast from
            // holder lane kk*8 (compile-time lane via unrolled kk).
            const int nk = (p < 3) ? 8 : 1;
            #pragma unroll
            for (int kk = 0; kk < 8; ++kk) {
                if (kk < nk) {
                    const int k2 = (p * 8 + kk) * 2;
                    const float4 w4a = cw4[(k2 + 0) * 64 + lane];
                    const float4 w4b = cw4[(k2 + 1) * 64 + lane];
                    acc2 = fmaf(w4a.x, __shfl(acc[0], kk * 8, 64), acc2);
                    acc2 = fmaf(w4a.y, __shfl(acc[1], kk * 8, 64), acc2);
                    acc2 = fmaf(w4a.z, __shfl(acc[2], kk * 8, 64), acc2);
                    acc2 = fmaf(w4a.w, __shfl(acc[3], kk * 8, 64), acc2);
                    acc2 = fmaf(w4b.x, __shfl(acc[4], kk * 8, 64), acc2);
                    acc2 = fmaf(w4b.y, __shfl(acc[5], kk * 8, 64), acc2);
                    acc2 = fmaf(w4b.z, __shfl(acc[6], kk * 8, 64), acc2);
                    acc2 = fmaf(w4b.w, __shfl(acc[7], kk * 8, 64), acc2);
                }
            }
        }
        xmid[((size_t)(b * M + m)) * 128 + s * 64 + lane] = fmaxf(acc2, 0.f);
    }
}

// ---------------- Kernel C0: MLP0 + relu (in-place xmid [col][128]) ----------------
__global__ __launch_bounds__(256) void mlp0_kernel(
    float* __restrict__ xmid,
    const float* __restrict__ w0T, const float* __restrict__ b0) {
    __shared__ float ws[128 * 128];   // 64 KB, [c][o]
    __shared__ float xs[128 * 32];    // 16 KB, [c][col]

    int tid = threadIdx.x;
    int col0 = blockIdx.x * TC;

    {
        const float4* w4 = (const float4*)w0T;
        float4* ws4 = (float4*)ws;
        #pragma unroll
        for (int i = 0; i < 16; ++i) ws4[tid + 256 * i] = w4[tid + 256 * i];
    }
    {
        const float4* xm4 = (const float4*)(xmid + (size_t)col0 * 128);
        #pragma unroll
        for (int r = tid; r < 1024; r += 256) {
            int lc = r >> 5, c4 = r & 31;
            float4 v = xm4[lc * 32 + c4];
            int c = c4 * 4;
            xs[(c + 0) * 32 + lc] = v.x;
            xs[(c + 1) * 32 + lc] = v.y;
            xs[(c + 2) * 32 + lc] = v.z;
            xs[(c + 3) * 32 + lc] = v.w;
        }
    }
    __syncthreads();

    int og = tid >> 3, cg = tid & 7;
    int o0 = og * 4, lc0 = cg * 4;
    float acc[4][4];
    #pragma unroll
    for (int i = 0; i < 4; ++i) {
        float bv = b0[o0 + i];
        #pragma unroll
        for (int u = 0; u < 4; ++u) acc[i][u] = bv;
    }
    for (int c = 0; c < 128; ++c) {
        float4 xv = *(const float4*)&xs[c * 32 + lc0];
        float4 wv = *(const float4*)&ws[c * 128 + o0];
        acc[0][0] = fmaf(wv.x, xv.x, acc[0][0]);
        acc[0][1] = fmaf(wv.x, xv.y, acc[0][1]);
        acc[0][2] = fmaf(wv.x, xv.z, acc[0][2]);
        acc[0][3] = fmaf(wv.x, xv.w, acc[0][3]);
        acc[1][0] = fmaf(wv.y, xv.x, acc[1][0]);
        acc[1][1] = fmaf(wv.y, xv.y, acc[1][1]);
        acc[1][2] = fmaf(wv.y, xv.z, acc[1][2]);
        acc[1][3] = fmaf(wv.y, xv.w, acc[1][3]);
        acc[2][0] = fmaf(wv.z, xv.x, acc[2][0]);
        acc[2][1] = fmaf(wv.z, xv.y, acc[2][1]);
        acc[2][2] = fmaf(wv.z, xv.z, acc[2][2]);
        acc[2][3] = fmaf(wv.z, xv.w, acc[2][3]);
        acc[3][0] = fmaf(wv.w, xv.x, acc[3][0]);
        acc[3][1] = fmaf(wv.w, xv.y, acc[3][1]);
        acc[3][2] = fmaf(wv.w, xv.z, acc[3][2]);
        acc[3][3] = fmaf(wv.w, xv.w, acc[3][3]);
    }
    #pragma unroll
    for (int u = 0; u < 4; ++u) {
        float4 v = make_float4(fmaxf(acc[0][u], 0.f), fmaxf(acc[1][u], 0.f),
                               fmaxf(acc[2][u], 0.f), fmaxf(acc[3][u], 0.f));
        *(float4*)&xmid[(size_t)(col0 + lc0 + u) * 128 + o0] = v;
    }
}

// ---------------- Kernel C1: MLP1 + relu + store (o-split) ----------------
__global__ __launch_bounds__(256) void mlp1_kernel(
    const float* __restrict__ xmid,
    const float* __restrict__ w1T, const float* __restrict__ b1,
    float* __restrict__ out_rf) {
    __shared__ float ws[128 * 128];   // 64 KB, [c][o-half]
    __shared__ float xs[128 * 32];    // 16 KB

    int tid = threadIdx.x;
    int bx = blockIdx.x;
    int col0 = (bx >> 1) * TC;
    int oH = (bx & 1) * 128;

    {
        for (int i = tid; i < 4096; i += 256) {
            int c = i >> 5, q = i & 31;
            *(float4*)&ws[c * 128 + q * 4] = *(const float4*)&w1T[c * 256 + oH + q * 4];
        }
    }
    {
        const float4* xm4 = (const float4*)(xmid + (size_t)col0 * 128);
        #pragma unroll
        for (int r = tid; r < 1024; r += 256) {
            int lc = r >> 5, c4 = r & 31;
            float4 v = xm4[lc * 32 + c4];
            int c = c4 * 4;
            xs[(c + 0) * 32 + lc] = v.x;
            xs[(c + 1) * 32 + lc] = v.y;
            xs[(c + 2) * 32 + lc] = v.z;
            xs[(c + 3) * 32 + lc] = v.w;
        }
    }
    __syncthreads();

    int og = tid >> 3, cg = tid & 7;
    int o0 = og * 4, lc0 = cg * 4;
    float acc[4][4];
    #pragma unroll
    for (int i = 0; i < 4; ++i) {
        float bv = b1[oH + o0 + i];
        #pragma unroll
        for (int u = 0; u < 4; ++u) acc[i][u] = bv;
    }
    for (int c = 0; c < 128; ++c) {
        float4 xv = *(const float4*)&xs[c * 32 + lc0];
        float4 wv = *(const float4*)&ws[c * 128 + o0];
        acc[0][0] = fmaf(wv.x, xv.x, acc[0][0]);
        acc[0][1] = fmaf(wv.x, xv.y, acc[0][1]);
        acc[0][2] = fmaf(wv.x, xv.z, acc[0][2]);
        acc[0][3] = fmaf(wv.x, xv.w, acc[0][3]);
        acc[1][0] = fmaf(wv.y, xv.x, acc[1][0]);
        acc[1][1] = fmaf(wv.y, xv.y, acc[1][1]);
        acc[1][2] = fmaf(wv.y, xv.z, acc[1][2]);
        acc[1][3] = fmaf(wv.y, xv.w, acc[1][3]);
        acc[2][0] = fmaf(wv.z, xv.x, acc[2][0]);
        acc[2][1] = fmaf(wv.z, xv.y, acc[2][1]);
        acc[2][2] = fmaf(wv.z, xv.z, acc[2][2]);
        acc[2][3] = fmaf(wv.z, xv.w, acc[2][3]);
        acc[3][0] = fmaf(wv.w, xv.x, acc[3][0]);
        acc[3][1] = fmaf(wv.w, xv.y, acc[3][1]);
        acc[3][2] = fmaf(wv.w, xv.z, acc[3][2]);
        acc[3][3] = fmaf(wv.w, xv.w, acc[3][3]);
    }
    #pragma unroll
    for (int u = 0; u < 4; ++u) {
        float4 v = make_float4(fmaxf(acc[0][u], 0.f), fmaxf(acc[1][u], 0.f),
                               fmaxf(acc[2][u], 0.f), fmaxf(acc[3][u], 0.f));
        *(float4*)&out_rf[(size_t)(col0 + lc0 + u) * 256 + oH + o0] = v;
    }
}

extern "C" void kernel_launch(void* const* d_in, const int* in_sizes, int n_in,
                              void* d_out, int out_size, void* d_ws, size_t ws_size,
                              hipStream_t stream) {
    const float* xyz     = (const float*)d_in[0];
    const float* feature = (const float*)d_in[1];
    const float* new_xyz = (const float*)d_in[2];
    const int*   idx     = (const int*)  d_in[3];
    const float* weight  = (const float*)d_in[4];
    const float* conv_w  = (const float*)d_in[5];
    const float* conv_b  = (const float*)d_in[6];
    const float* mlp_w0  = (const float*)d_in[7];
    const float* mlp_b0  = (const float*)d_in[8];
    const float* mlp_w1  = (const float*)d_in[9];
    const float* mlp_b1  = (const float*)d_in[10];

    float* out    = (float*)d_out;
    float* out_rf = out + (size_t)B * M * 3;

    float* wsf = (float*)d_ws;
    __hip_bfloat16* xfh = (__hip_bfloat16*)wsf;  // 320000 bf16
    float* conv_wT = wsf + 160000;               // 13312
    float* xmid    = conv_wT + 13312;            // B*M*128, [col][c]
    float* w0T     = xmid + 1048576;             // 16384
    float* w1T     = w0T + 16384;                // 32768

    {
        int total = 320000 + 13312 + 24576 + 16384 + 32768;
        int blocks = (total + 255) / 256;
        prep_kernel<<<blocks, 256, 0, stream>>>(xyz, feature, new_xyz, conv_w,
                                                mlp_w0, mlp_w1,
                                                xfh, conv_wT, w0T, w1T, out);
    }
    {
        int blocks = (S * B * M) / GPB;         // 256
        gather_conv_kernel<<<blocks, NTH, 0, stream>>>(idx, weight, new_xyz,
                                                       (const uint4*)xfh,
                                                       conv_wT, conv_b, xmid);
    }
    {
        mlp0_kernel<<<(B * M) / TC, 256, 0, stream>>>(xmid, w0T, mlp_b0);
    }
    {
        mlp1_kernel<<<2 * (B * M) / TC, 256, 0, stream>>>(xmid, w1T, mlp_b1, out_rf);
    }
}